// Round 4
// baseline (172.019 us; speedup 1.0000x reference)
//
#include <hip/hip_runtime.h>
#include <hip/hip_bf16.h>

typedef __attribute__((ext_vector_type(4))) float  f32x4;
typedef __attribute__((ext_vector_type(8))) short  s16x8;

#define D_MODEL 2048
#define SEQ     4096
#define BATCH   4
#define NATOMS  64
#define RANK    6
#define NLAYERS 16
#define NAR     (NATOMS*RANK)     /* 384 */
#define M_TOTAL (BATCH*SEQ)       /* 16384 */

#define ASZ  (64*72)    /* shorts per A buffer (+8 pad) */

static __device__ __forceinline__ unsigned short f2bf(float x){
    union { float f; unsigned u; } v; v.f = x;
    unsigned r = (v.u + 0x7FFF + ((v.u >> 16) & 1)) >> 16;
    return (unsigned short)r;
}

static __device__ __forceinline__ s16x8 cvt8(f32x4 lo, f32x4 hi) {
    union { s16x8 v; unsigned short s[8]; } u;
    u.s[0] = f2bf(lo.x); u.s[1] = f2bf(lo.y); u.s[2] = f2bf(lo.z); u.s[3] = f2bf(lo.w);
    u.s[4] = f2bf(hi.x); u.s[5] = f2bf(hi.y); u.s[6] = f2bf(hi.z); u.s[7] = f2bf(hi.w);
    return u.v;
}

// ---------------------------------------------------------------------------
// Prep: gather layer slice, cast to bf16, lay out K-contiguous.
//   WbfT[n][d]  (n = a*6+r)   from A[a, l, d, r]
//   BbfT[p][n]                from B[a, l, r, p]
// ---------------------------------------------------------------------------
__global__ void prep_kernel(const float* __restrict__ A,
                            const float* __restrict__ B,
                            const int*   __restrict__ layer_idx,
                            unsigned short* __restrict__ WbfT,
                            unsigned short* __restrict__ BbfT)
{
    const int l = layer_idx[0];
    int idx = blockIdx.x * 256 + threadIdx.x;
    const int total = NAR * D_MODEL;   // 786432
    if (idx < total) {
        int n = idx / D_MODEL, d = idx % D_MODEL;
        int a = n / RANK, r = n % RANK;
        float v = A[((size_t)(a*NLAYERS + l) * D_MODEL + d) * RANK + r];
        WbfT[idx] = f2bf(v);
    } else {
        idx -= total;
        int p = idx / NAR, n = idx % NAR;
        int a = n / RANK, r = n % RANK;
        float v = B[((size_t)(a*NLAYERS + l) * RANK + r) * D_MODEL + p];
        BbfT[idx] = f2bf(v);
    }
}

// ---------------------------------------------------------------------------
// GEMM1: P[m][n] = f2bf( scale[b, n/6] * sum_d hidden[m][d] * WbfT[n][d] )
//   M=16384, K=2048, N=384.  BM=64, BN=128, BK=64, 4 waves (2x2).
//   W (1.5 MB, L2-resident) loaded DIRECT global->reg inside the MFMA loop —
//   no W LDS, no vmcnt at barriers.  A reg-staged fp32->bf16 into padded
//   double-buffered LDS; per-iter barrier is lgkmcnt(0)-only.
// ---------------------------------------------------------------------------
__global__ __launch_bounds__(256, 3) void gemm1(
    const float*          __restrict__ hidden,  // [16384][2048] fp32
    const float*          __restrict__ scales,  // [4][64]
    const unsigned short* __restrict__ WbfT,    // [384][2048] bf16
    unsigned short*       __restrict__ P)       // [16384][384] bf16
{
    __shared__ __align__(16) unsigned short Af[2 * ASZ];   // 18.4 KB

    // XCD-aware swizzle (nwg=768, 768%8==0 -> bijective); groups the 3
    // n-blocks sharing one hidden panel onto the same XCD's L2.
    int wg = (int)blockIdx.x;
    wg = (wg & 7) * 96 + (wg >> 3);
    const int m0 = (wg / 3) * 64;
    const int n0 = (wg % 3) * 128;

    const int tid  = threadIdx.x;
    const int lane = tid & 63;
    const int wave = tid >> 6;
    const int wr   = wave >> 1, wc = wave & 1;

    // A staging: thread owns row rA, 16 floats starting at float-col cA
    const int rA = tid >> 2;
    const int cA = (tid & 3) << 4;
    const float* srcA = &hidden[(size_t)(m0 + rA) * D_MODEL + cA];

    // W direct-load base: row = n0 + wc*64 + (lane&15), k-offset (lane>>4)*8
    const unsigned short* Wbase =
        &WbfT[(size_t)(n0 + wc * 64 + (lane & 15)) * D_MODEL + (lane >> 4) * 8];

    f32x4 acc[2][4] = {};
    f32x4 g[4];

    // ---- prologue: stage A tile 0 ----
    #pragma unroll
    for (int q = 0; q < 4; ++q) g[q] = *reinterpret_cast<const f32x4*>(srcA + q * 4);
    srcA += 64;
    {
        s16x8 s0 = cvt8(g[0], g[1]);
        s16x8 s1 = cvt8(g[2], g[3]);
        *reinterpret_cast<s16x8*>(&Af[rA * 72 + cA])     = s0;
        *reinterpret_cast<s16x8*>(&Af[rA * 72 + cA + 8]) = s1;
    }
    asm volatile("s_waitcnt lgkmcnt(0)" ::: "memory");
    __builtin_amdgcn_s_barrier();

    int ab = 0;
    for (int t = 0; t < 32; ++t) {
        const int k0 = t * 64;
        // 1. issue A(t+1) register loads (latency hidden by compute below)
        if (t < 31) {
            #pragma unroll
            for (int q = 0; q < 4; ++q) g[q] = *reinterpret_cast<const f32x4*>(srcA + q * 4);
            srcA += 64;
        }
        // 2. compute tile t: B-frags direct from L2, A-frags from LDS
        const unsigned short* Ar = &Af[ab * ASZ];
        #pragma unroll
        for (int kk = 0; kk < 2; ++kk) {
            const int krow = kk * 32 + (lane >> 4) * 8;
            s16x8 bfr[4], afr[2];
            #pragma unroll
            for (int ni = 0; ni < 4; ++ni)
                bfr[ni] = *reinterpret_cast<const s16x8*>(
                    Wbase + (size_t)ni * 16 * D_MODEL + k0 + kk * 32);
            #pragma unroll
            for (int mi = 0; mi < 2; ++mi) {
                int ar = wr * 32 + mi * 16 + (lane & 15);
                afr[mi] = *reinterpret_cast<const s16x8*>(&Ar[ar * 72 + krow]);
            }
            __builtin_amdgcn_s_setprio(1);
            #pragma unroll
            for (int mi = 0; mi < 2; ++mi)
                #pragma unroll
                for (int ni = 0; ni < 4; ++ni)
                    acc[mi][ni] = __builtin_amdgcn_mfma_f32_16x16x32_bf16(
                        afr[mi], bfr[ni], acc[mi][ni], 0, 0, 0);
            __builtin_amdgcn_s_setprio(0);
        }
        // 3. cvt A(t+1) -> other LDS buffer, then lgkmcnt-only barrier
        if (t < 31) {
            s16x8 s0 = cvt8(g[0], g[1]);
            s16x8 s1 = cvt8(g[2], g[3]);
            *reinterpret_cast<s16x8*>(&Af[(ab ^ 1) * ASZ + rA * 72 + cA])     = s0;
            *reinterpret_cast<s16x8*>(&Af[(ab ^ 1) * ASZ + rA * 72 + cA + 8]) = s1;
            asm volatile("s_waitcnt lgkmcnt(0)" ::: "memory");
            __builtin_amdgcn_s_barrier();
            ab ^= 1;
        }
    }

    // ---- epilogue: scale by atom_scales[b, n/6], store bf16 ----
    const int b    = m0 >> 12;
    const int row0 = m0 + wr * 32;
    const int col0 = n0 + wc * 64;
    #pragma unroll
    for (int ni = 0; ni < 4; ++ni) {
        int col  = col0 + ni * 16 + (lane & 15);
        float sc = scales[b * NATOMS + col / RANK];
        #pragma unroll
        for (int mi = 0; mi < 2; ++mi) {
            #pragma unroll
            for (int r = 0; r < 4; ++r) {
                int row = row0 + mi * 16 + (lane >> 4) * 4 + r;
                P[(size_t)row * NAR + col] = f2bf(acc[mi][ni][r] * sc);
            }
        }
    }
}

// ---------------------------------------------------------------------------
// GEMM2: out[m][p] = sum_n P[m][n] * BbfT[p][n]   (at HBM roofline)
// ---------------------------------------------------------------------------
__global__ __launch_bounds__(256, 2) void gemm2(
    const unsigned short* __restrict__ P,     // [16384][384] bf16
    const unsigned short* __restrict__ BbfT,  // [2048][384] bf16
    float*                __restrict__ out)   // [16384][2048] fp32
{
    __shared__ unsigned short Pt[128][72];
    __shared__ unsigned short Bt[128][72];

    const int m0   = blockIdx.x * 128;
    const int p0   = blockIdx.y * 128;
    const int tid  = threadIdx.x;
    const int lane = tid & 63;
    const int wave = tid >> 6;
    const int wr   = wave >> 1, wc = wave & 1;

    f32x4 acc[4][4] = {};

    for (int k0 = 0; k0 < NAR; k0 += 64) {
        #pragma unroll
        for (int pass = 0; pass < 4; ++pass) {
            int c   = tid + pass * 256;
            int row = c >> 3, c8 = c & 7;
            s16x8 v = *reinterpret_cast<const s16x8*>(
                &P[(size_t)(m0 + row) * NAR + k0 + c8 * 8]);
            *reinterpret_cast<s16x8*>(&Pt[row][c8 * 8]) = v;
        }
        #pragma unroll
        for (int pass = 0; pass < 4; ++pass) {
            int c   = tid + pass * 256;
            int row = c >> 3, c8 = c & 7;
            s16x8 v = *reinterpret_cast<const s16x8*>(
                &BbfT[(size_t)(p0 + row) * NAR + k0 + c8 * 8]);
            *reinterpret_cast<s16x8*>(&Bt[row][c8 * 8]) = v;
        }
        __syncthreads();

        #pragma unroll
        for (int kk = 0; kk < 64; kk += 32) {
            const int krow = kk + (lane >> 4) * 8;
            s16x8 a_frag[4], b_frag[4];
            #pragma unroll
            for (int mi = 0; mi < 4; ++mi)
                a_frag[mi] = *reinterpret_cast<const s16x8*>(
                    &Pt[wr * 64 + mi * 16 + (lane & 15)][krow]);
            #pragma unroll
            for (int ni = 0; ni < 4; ++ni)
                b_frag[ni] = *reinterpret_cast<const s16x8*>(
                    &Bt[wc * 64 + ni * 16 + (lane & 15)][krow]);
            #pragma unroll
            for (int mi = 0; mi < 4; ++mi)
                #pragma unroll
                for (int ni = 0; ni < 4; ++ni)
                    acc[mi][ni] = __builtin_amdgcn_mfma_f32_16x16x32_bf16(
                        a_frag[mi], b_frag[ni], acc[mi][ni], 0, 0, 0);
        }
        __syncthreads();
    }

    const int row0 = m0 + wr * 64;
    const int col0 = p0 + wc * 64;
    #pragma unroll
    for (int mi = 0; mi < 4; ++mi) {
        #pragma unroll
        for (int ni = 0; ni < 4; ++ni) {
            int col = col0 + ni * 16 + (lane & 15);
            #pragma unroll
            for (int r = 0; r < 4; ++r) {
                int row = row0 + mi * 16 + (lane >> 4) * 4 + r;
                out[(size_t)row * D_MODEL + col] = acc[mi][ni][r];
            }
        }
    }
}

extern "C" void kernel_launch(void* const* d_in, const int* in_sizes, int n_in,
                              void* d_out, int out_size, void* d_ws, size_t ws_size,
                              hipStream_t stream)
{
    const float* hidden    = (const float*)d_in[0];
    const float* scales    = (const float*)d_in[1];
    const float* A         = (const float*)d_in[2];
    const float* B         = (const float*)d_in[3];
    const int*   layer_idx = (const int*)d_in[4];
    float* out = (float*)d_out;

    unsigned short* WbfT = (unsigned short*)d_ws;            // [384][2048]
    unsigned short* BbfT = WbfT + (size_t)NAR * D_MODEL;     // [2048][384]
    unsigned short* P    = BbfT + (size_t)D_MODEL * NAR;     // [16384][384]

    prep_kernel<<<(2 * NAR * D_MODEL) / 256, 256, 0, stream>>>(A, B, layer_idx, WbfT, BbfT);
    gemm1<<<M_TOTAL / 64 * (NAR / 128), 256, 0, stream>>>(hidden, scales, WbfT, P);
    gemm2<<<dim3(M_TOTAL / 128, D_MODEL / 128), 256, 0, stream>>>(P, BbfT, out);
}

// Round 5
// 114.771 us; speedup vs baseline: 1.4988x; 1.4988x over previous
//
#include <hip/hip_runtime.h>
#include <hip/hip_bf16.h>

typedef __attribute__((ext_vector_type(4))) float  f32x4;
typedef __attribute__((ext_vector_type(8))) short  s16x8;

#define D_MODEL 2048
#define SEQ     4096
#define BATCH   4
#define NATOMS  64
#define RANK    6
#define NLAYERS 16
#define NAR     (NATOMS*RANK)     /* 384 */
#define M_TOTAL (BATCH*SEQ)       /* 16384 */

#define WFSZ (128*64)   /* shorts per W buffer */
#define ASZ  (64*72)    /* shorts per A buffer (+8 pad) */

static __device__ __forceinline__ unsigned short f2bf(float x){
    union { float f; unsigned u; } v; v.f = x;
    unsigned r = (v.u + 0x7FFF + ((v.u >> 16) & 1)) >> 16;
    return (unsigned short)r;
}

static __device__ __forceinline__ void gload_lds16(const void* g, void* l) {
    __builtin_amdgcn_global_load_lds(
        (const __attribute__((address_space(1))) unsigned int*)g,
        (__attribute__((address_space(3))) unsigned int*)l, 16, 0, 0);
}

static __device__ __forceinline__ s16x8 cvt8(f32x4 lo, f32x4 hi) {
    union { s16x8 v; unsigned short s[8]; } u;
    u.s[0] = f2bf(lo.x); u.s[1] = f2bf(lo.y); u.s[2] = f2bf(lo.z); u.s[3] = f2bf(lo.w);
    u.s[4] = f2bf(hi.x); u.s[5] = f2bf(hi.y); u.s[6] = f2bf(hi.z); u.s[7] = f2bf(hi.w);
    return u.v;
}

// ---------------------------------------------------------------------------
// Prep: gather layer slice, cast to bf16, lay out K-contiguous.
// ---------------------------------------------------------------------------
__global__ void prep_kernel(const float* __restrict__ A,
                            const float* __restrict__ B,
                            const int*   __restrict__ layer_idx,
                            unsigned short* __restrict__ WbfT,
                            unsigned short* __restrict__ BbfT)
{
    const int l = layer_idx[0];
    int idx = blockIdx.x * 256 + threadIdx.x;
    const int total = NAR * D_MODEL;   // 786432
    if (idx < total) {
        int n = idx / D_MODEL, d = idx % D_MODEL;
        int a = n / RANK, r = n % RANK;
        float v = A[((size_t)(a*NLAYERS + l) * D_MODEL + d) * RANK + r];
        WbfT[idx] = f2bf(v);
    } else {
        idx -= total;
        int p = idx / NAR, n = idx % NAR;
        int a = n / RANK, r = n % RANK;
        float v = B[((size_t)(a*NLAYERS + l) * RANK + r) * D_MODEL + p];
        BbfT[idx] = f2bf(v);
    }
}

// ---------------------------------------------------------------------------
// GEMM1: P[m][n] = f2bf( scale[b, n/6] * sum_d hidden[m][d] * WbfT[n][d] )
//   M=16384, K=2048, N=384.  BM=64, BN=128, BK=64, 4 waves (2x2).
//   R2 structure (51.2 KB LDS, 3 blocks/CU) + A 2-deep reg prefetch (named
//   g0/g1 sets, 2-unrolled loop) + counted vmcnt(4) at the barrier so the
//   in-flight A(t+2) HBM loads cross the barrier.  W dbuf via gload_lds
//   (linear dest, XOR-preswizzled source, XOR read).
// ---------------------------------------------------------------------------
__global__ __launch_bounds__(256, 3) void gemm1(
    const float*          __restrict__ hidden,  // [16384][2048] fp32
    const float*          __restrict__ scales,  // [4][64]
    const unsigned short* __restrict__ WbfT,    // [384][2048] bf16
    unsigned short*       __restrict__ P)       // [16384][384] bf16
{
    __shared__ __align__(16) unsigned short Af[2*ASZ];   // 18.4 KB
    __shared__ __align__(16) unsigned short Wf[2*WFSZ];  // 32 KB

    // XCD-aware swizzle (nwg=768, 768%8==0 -> bijective). Consecutive wg
    // (the 3 n-blocks of one m-panel) stay on one XCD's L2.
    int wg = (int)blockIdx.x;
    wg = (wg & 7) * 96 + (wg >> 3);
    const int m0 = (wg / 3) * 64;
    const int n0 = (wg % 3) * 128;

    const int tid  = threadIdx.x;
    const int lane = tid & 63;
    const int wave = tid >> 6;
    const int wr   = wave >> 1, wc = wave & 1;

    // A staging: thread owns row rA, 16 floats starting at float-col cA
    const int rA = tid >> 2;
    const int cA = (tid & 3) << 4;
    const float* srcA = &hidden[(size_t)(m0 + rA) * D_MODEL + cA];

    // W staging: 16 gload_lds of 1KB; wave w does insts i = w*4+j.
    // inst i, lane l -> LDS row r = i*8 + (l>>3), chunk c = l&7 (16B);
    // source pre-swizzled: LDS chunk c holds global chunk c^(r&7).
    const unsigned short* srcW[4];
    int ldsWoff[4];
    #pragma unroll
    for (int j = 0; j < 4; ++j) {
        int i = wave * 4 + j;
        int r = i * 8 + (lane >> 3);
        int c = (lane & 7) ^ (r & 7);
        srcW[j]    = &WbfT[(size_t)(n0 + r) * D_MODEL + c * 8];
        ldsWoff[j] = i * 512;  // shorts
    }

    f32x4 acc[2][4] = {};
    f32x4 g0[4], g1[4];

    // ---- prologue ----
    // A(0) -> regs -> Af[0]
    #pragma unroll
    for (int q = 0; q < 4; ++q) g1[q] = *reinterpret_cast<const f32x4*>(srcA + q * 4);
    srcA += 64;
    {
        s16x8 s0 = cvt8(g1[0], g1[1]);
        s16x8 s1 = cvt8(g1[2], g1[3]);
        *reinterpret_cast<s16x8*>(&Af[rA * 72 + cA])     = s0;
        *reinterpret_cast<s16x8*>(&Af[rA * 72 + cA + 8]) = s1;
    }
    // W(0) in flight; A(1) in flight (stays in flight across barrier)
    #pragma unroll
    for (int j = 0; j < 4; ++j) { gload_lds16(srcW[j], &Wf[ldsWoff[j]]); srcW[j] += 64; }
    #pragma unroll
    for (int q = 0; q < 4; ++q) g1[q] = *reinterpret_cast<const f32x4*>(srcA + q * 4);
    srcA += 64;
    asm volatile("s_waitcnt vmcnt(4) lgkmcnt(0)" ::: "memory");  // drain W(0) only
    __builtin_amdgcn_s_barrier();

    // ---- main loop: iter t computes tile t from Af/Wf[t&1] ----
    // per iter: issue W(t+1); issue A(t+2) into gIss; compute; cvt gCvt
    // (= A(t+1), loaded at t-1); barrier vmcnt(4) keeps A(t+2) in flight.
    auto body = [&](int t, f32x4 (&gIss)[4], f32x4 (&gCvt)[4]) {
        const int buf = t & 1;
        if (t < 31) {
            #pragma unroll
            for (int j = 0; j < 4; ++j) {
                gload_lds16(srcW[j], &Wf[(buf ^ 1) * WFSZ + ldsWoff[j]]);
                srcW[j] += 64;
            }
        }
        if (t < 30) {
            #pragma unroll
            for (int q = 0; q < 4; ++q) gIss[q] = *reinterpret_cast<const f32x4*>(srcA + q * 4);
            srcA += 64;
        }
        const unsigned short* Ar = &Af[buf * ASZ];
        const unsigned short* Wr = &Wf[buf * WFSZ];
        #pragma unroll
        for (int kk = 0; kk < 2; ++kk) {
            const int krow = kk * 32 + (lane >> 4) * 8;
            const int kch  = krow >> 3;
            s16x8 bfr[4], afr[2];
            #pragma unroll
            for (int ni = 0; ni < 4; ++ni) {
                int br = wc * 64 + ni * 16 + (lane & 15);
                bfr[ni] = *reinterpret_cast<const s16x8*>(
                    &Wr[br * 64 + ((kch ^ (br & 7)) << 3)]);
            }
            #pragma unroll
            for (int mi = 0; mi < 2; ++mi) {
                int ar = wr * 32 + mi * 16 + (lane & 15);
                afr[mi] = *reinterpret_cast<const s16x8*>(&Ar[ar * 72 + krow]);
            }
            #pragma unroll
            for (int mi = 0; mi < 2; ++mi)
                #pragma unroll
                for (int ni = 0; ni < 4; ++ni)
                    acc[mi][ni] = __builtin_amdgcn_mfma_f32_16x16x32_bf16(
                        afr[mi], bfr[ni], acc[mi][ni], 0, 0, 0);
        }
        if (t < 31) {
            s16x8 s0 = cvt8(gCvt[0], gCvt[1]);
            s16x8 s1 = cvt8(gCvt[2], gCvt[3]);
            *reinterpret_cast<s16x8*>(&Af[(buf ^ 1) * ASZ + rA * 72 + cA])     = s0;
            *reinterpret_cast<s16x8*>(&Af[(buf ^ 1) * ASZ + rA * 72 + cA + 8]) = s1;
            if (t == 30) asm volatile("s_waitcnt vmcnt(0) lgkmcnt(0)" ::: "memory");
            else         asm volatile("s_waitcnt vmcnt(4) lgkmcnt(0)" ::: "memory");
            __builtin_amdgcn_s_barrier();
        }
    };
    for (int tt = 0; tt < 32; tt += 2) {
        body(tt,     g0, g1);   // issues A(tt+2) into g0, cvts A(tt+1) from g1
        body(tt + 1, g1, g0);
    }

    // ---- epilogue: scale by atom_scales[b, n/6], store bf16 ----
    const int b    = m0 >> 12;
    const int row0 = m0 + wr * 32;
    const int col0 = n0 + wc * 64;
    #pragma unroll
    for (int ni = 0; ni < 4; ++ni) {
        int col  = col0 + ni * 16 + (lane & 15);
        float sc = scales[b * NATOMS + col / RANK];
        #pragma unroll
        for (int mi = 0; mi < 2; ++mi) {
            #pragma unroll
            for (int r = 0; r < 4; ++r) {
                int row = row0 + mi * 16 + (lane >> 4) * 4 + r;
                P[(size_t)row * NAR + col] = f2bf(acc[mi][ni][r] * sc);
            }
        }
    }
}

// ---------------------------------------------------------------------------
// GEMM2: out[m][p] = sum_n P[m][n] * BbfT[p][n]   (at HBM roofline)
// ---------------------------------------------------------------------------
__global__ __launch_bounds__(256, 2) void gemm2(
    const unsigned short* __restrict__ P,     // [16384][384] bf16
    const unsigned short* __restrict__ BbfT,  // [2048][384] bf16
    float*                __restrict__ out)   // [16384][2048] fp32
{
    __shared__ unsigned short Pt[128][72];
    __shared__ unsigned short Bt[128][72];

    const int m0   = blockIdx.x * 128;
    const int p0   = blockIdx.y * 128;
    const int tid  = threadIdx.x;
    const int lane = tid & 63;
    const int wave = tid >> 6;
    const int wr   = wave >> 1, wc = wave & 1;

    f32x4 acc[4][4] = {};

    for (int k0 = 0; k0 < NAR; k0 += 64) {
        #pragma unroll
        for (int pass = 0; pass < 4; ++pass) {
            int c   = tid + pass * 256;
            int row = c >> 3, c8 = c & 7;
            s16x8 v = *reinterpret_cast<const s16x8*>(
                &P[(size_t)(m0 + row) * NAR + k0 + c8 * 8]);
            *reinterpret_cast<s16x8*>(&Pt[row][c8 * 8]) = v;
        }
        #pragma unroll
        for (int pass = 0; pass < 4; ++pass) {
            int c   = tid + pass * 256;
            int row = c >> 3, c8 = c & 7;
            s16x8 v = *reinterpret_cast<const s16x8*>(
                &BbfT[(size_t)(p0 + row) * NAR + k0 + c8 * 8]);
            *reinterpret_cast<s16x8*>(&Bt[row][c8 * 8]) = v;
        }
        __syncthreads();

        #pragma unroll
        for (int kk = 0; kk < 64; kk += 32) {
            const int krow = kk + (lane >> 4) * 8;
            s16x8 a_frag[4], b_frag[4];
            #pragma unroll
            for (int mi = 0; mi < 4; ++mi)
                a_frag[mi] = *reinterpret_cast<const s16x8*>(
                    &Pt[wr * 64 + mi * 16 + (lane & 15)][krow]);
            #pragma unroll
            for (int ni = 0; ni < 4; ++ni)
                b_frag[ni] = *reinterpret_cast<const s16x8*>(
                    &Bt[wc * 64 + ni * 16 + (lane & 15)][krow]);
            #pragma unroll
            for (int mi = 0; mi < 4; ++mi)
                #pragma unroll
                for (int ni = 0; ni < 4; ++ni)
                    acc[mi][ni] = __builtin_amdgcn_mfma_f32_16x16x32_bf16(
                        a_frag[mi], b_frag[ni], acc[mi][ni], 0, 0, 0);
        }
        __syncthreads();
    }

    const int row0 = m0 + wr * 64;
    const int col0 = p0 + wc * 64;
    #pragma unroll
    for (int mi = 0; mi < 4; ++mi) {
        #pragma unroll
        for (int ni = 0; ni < 4; ++ni) {
            int col = col0 + ni * 16 + (lane & 15);
            #pragma unroll
            for (int r = 0; r < 4; ++r) {
                int row = row0 + mi * 16 + (lane >> 4) * 4 + r;
                out[(size_t)row * D_MODEL + col] = acc[mi][ni][r];
            }
        }
    }
}

extern "C" void kernel_launch(void* const* d_in, const int* in_sizes, int n_in,
                              void* d_out, int out_size, void* d_ws, size_t ws_size,
                              hipStream_t stream)
{
    const float* hidden    = (const float*)d_in[0];
    const float* scales    = (const float*)d_in[1];
    const float* A         = (const float*)d_in[2];
    const float* B         = (const float*)d_in[3];
    const int*   layer_idx = (const int*)d_in[4];
    float* out = (float*)d_out;

    unsigned short* WbfT = (unsigned short*)d_ws;            // [384][2048]
    unsigned short* BbfT = WbfT + (size_t)NAR * D_MODEL;     // [2048][384]
    unsigned short* P    = BbfT + (size_t)D_MODEL * NAR;     // [16384][384]

    prep_kernel<<<(2 * NAR * D_MODEL) / 256, 256, 0, stream>>>(A, B, layer_idx, WbfT, BbfT);
    gemm1<<<M_TOTAL / 64 * (NAR / 128), 256, 0, stream>>>(hidden, scales, WbfT, P);
    gemm2<<<dim3(M_TOTAL / 128, D_MODEL / 128), 256, 0, stream>>>(P, BbfT, out);
}